// Round 9
// baseline (60.990 us; speedup 1.0000x reference)
//
#include <hip/hip_runtime.h>
#include <math.h>

#define H 2048
#define DIN 1024
#define DOUT 1024
#define NL 4

__device__ __forceinline__ float wave_reduce_sum(float v) {
    #pragma unroll
    for (int off = 32; off; off >>= 1) v += __shfl_down(v, off);
    return v;
}
__device__ __forceinline__ float dot4(float4 w, float4 v, float a) {
    return fmaf(w.x, v.x, fmaf(w.y, v.y, fmaf(w.z, v.z, fmaf(w.w, v.w, a))));
}

// Generic GEMV: y[r] = dot(W[r,:], x) + b[r]. One 64-lane wave per row.
template <int K>
__global__ __launch_bounds__(256) void gemv_kernel(
    const float* __restrict__ W, const float* __restrict__ x,
    const float* __restrict__ b, float* __restrict__ y, int N) {
    int wave = (blockIdx.x * blockDim.x + threadIdx.x) >> 6;
    int lane = threadIdx.x & 63;
    if (wave >= N) return;
    const float* row = W + (size_t)wave * K;
    float acc = 0.f;
    #pragma unroll
    for (int i = 0; i < K / 256; ++i) {
        int idx = i * 256 + lane * 4;
        acc = dot4(*reinterpret_cast<const float4*>(row + idx),
                   *reinterpret_cast<const float4*>(x + idx), acc);
    }
    acc = wave_reduce_sum(acc);
    if (lane == 0) y[wave] = acc + b[wave];
}

// Per-layer GRU step, one 3-wave block per output element e.
// Wave w (= gate g in {r,z,n}) computes the FULL W_ih[g*H+e,:]·carry dot with
// 8 fully-unrolled unconditional float4 load pairs (deep, branch-free load
// pipeline), then a separate hv/W_hh loop with the exact-zero chunk skip
// (bit-identical: fmaf(w,0,acc)==acc for finite w; skips the 201 MB W_hh
// stream when h0==0). LDS-combine 3x2 partials; wave 0 does the gate math.
__global__ __launch_bounds__(192) void gru_layer_kernel(
    const float* __restrict__ Wi,    // [3H, H] this layer
    const float* __restrict__ Wh,    // [3H, H] this layer
    const float* __restrict__ bi,    // [3H]
    const float* __restrict__ bh,    // [3H]
    const float* __restrict__ hprev, // [H] = h0[l]
    const float* __restrict__ cin,   // [H]
    float* __restrict__ cout,        // [H]
    float* __restrict__ hid_out) {   // [H] slice of d_out
    const int e    = blockIdx.x;          // output element, 0..H-1
    const int wid  = threadIdx.x >> 6;    // gate 0=r, 1=z, 2=n
    const int lane = threadIdx.x & 63;

    const float* wrow = Wi + (size_t)(e + wid * H) * H;
    const float* hrow = Wh + (size_t)(e + wid * H) * H;

    // Dot 1: W_ih row · carry (unconditional, fully pipelined)
    float ai = 0.f;
    #pragma unroll
    for (int p = 0; p < H / 256; ++p) {
        int idx = p * 256 + lane * 4;
        ai = dot4(*reinterpret_cast<const float4*>(wrow + idx),
                  *reinterpret_cast<const float4*>(cin + idx), ai);
    }
    // Dot 2: W_hh row · h0[l] with zero-chunk skip (h0 is 8 KB, L1/L2-hot)
    float ah = 0.f;
    #pragma unroll
    for (int p = 0; p < H / 256; ++p) {
        int idx = p * 256 + lane * 4;
        float4 hv = *reinterpret_cast<const float4*>(hprev + idx);
        int nz = (hv.x != 0.f) || (hv.y != 0.f) || (hv.z != 0.f) || (hv.w != 0.f);
        if (__any(nz))
            ah = dot4(*reinterpret_cast<const float4*>(hrow + idx), hv, ah);
    }
    ai = wave_reduce_sum(ai);
    ah = wave_reduce_sum(ah);

    __shared__ float part[3][2];
    if (lane == 0) { part[wid][0] = ai; part[wid][1] = ah; }
    __syncthreads();
    if (threadIdx.x == 0) {
        float r = 1.f / (1.f + expf(-(part[0][0] + bi[e] + part[0][1] + bh[e])));
        float z = 1.f / (1.f + expf(-(part[1][0] + bi[H + e] + part[1][1] + bh[H + e])));
        float n = tanhf(part[2][0] + bi[2 * H + e] + r * (part[2][1] + bh[2 * H + e]));
        float h = hprev[e];
        float hnew = (1.f - z) * n + z * h;
        cout[e] = hnew;
        hid_out[e] = hnew;
    }
}

extern "C" void kernel_launch(void* const* d_in, const int* in_sizes, int n_in,
                              void* d_out, int out_size, void* d_ws, size_t ws_size,
                              hipStream_t stream) {
    const float* x    = (const float*)d_in[0];
    const float* h0   = (const float*)d_in[1];
    const float* encW = (const float*)d_in[2];
    const float* encb = (const float*)d_in[3];
    const float* Wih  = (const float*)d_in[4];
    const float* Whh  = (const float*)d_in[5];
    const float* bih  = (const float*)d_in[6];
    const float* bhh  = (const float*)d_in[7];
    const float* decW = (const float*)d_in[8];
    const float* decb = (const float*)d_in[9];
    float* out = (float*)d_out;

    float* vec0 = (float*)d_ws;      // [H]
    float* vec1 = vec0 + H;          // [H]

    // 1) encoder: [1,1024] -> [1,2048]
    gemv_kernel<DIN><<<H / 4, 256, 0, stream>>>(encW, x, encb, vec0, H);
    // 2) sequential fused GRU layers, ping-pong carry; 3-wave block per element
    const float* cin = vec0;
    float* cout = vec1;
    for (int l = 0; l < NL; ++l) {
        gru_layer_kernel<<<H, 192, 0, stream>>>(
            Wih + (size_t)l * 3 * H * H, Whh + (size_t)l * 3 * H * H,
            bih + l * 3 * H, bhh + l * 3 * H,
            h0 + l * H, cin, cout, out + DOUT + l * H);
        float* t = cout; cout = (float*)cin; cin = t;
    }
    // 3) decoder: [1,2048] -> [1,1024]
    gemv_kernel<H><<<DOUT / 4, 256, 0, stream>>>(decW, cin, decb, out, DOUT);
}

// Round 10
// 56.074 us; speedup vs baseline: 1.0877x; 1.0877x over previous
//
#include <hip/hip_runtime.h>
#include <math.h>

#define H 2048
#define DIN 1024
#define DOUT 1024
#define NL 4

__device__ __forceinline__ float wave_reduce_sum(float v) {
    #pragma unroll
    for (int off = 32; off; off >>= 1) v += __shfl_down(v, off);
    return v;
}
__device__ __forceinline__ float dot4(float4 w, float4 v, float a) {
    return fmaf(w.x, v.x, fmaf(w.y, v.y, fmaf(w.z, v.z, fmaf(w.w, v.w, a))));
}

// Generic GEMV: y[r] = dot(W[r,:], x) + b[r]. One 64-lane wave per row.
template <int K>
__global__ __launch_bounds__(256) void gemv_kernel(
    const float* __restrict__ W, const float* __restrict__ x,
    const float* __restrict__ b, float* __restrict__ y, int N) {
    int wave = (blockIdx.x * blockDim.x + threadIdx.x) >> 6;
    int lane = threadIdx.x & 63;
    if (wave >= N) return;
    const float* row = W + (size_t)wave * K;
    float acc = 0.f;
    #pragma unroll
    for (int i = 0; i < K / 256; ++i) {
        int idx = i * 256 + lane * 4;
        acc = dot4(*reinterpret_cast<const float4*>(row + idx),
                   *reinterpret_cast<const float4*>(x + idx), acc);
    }
    acc = wave_reduce_sum(acc);
    if (lane == 0) y[wave] = acc + b[wave];
}

// Per-layer GRU step (R8 launch shape: wave per output element, 512x256).
// R10 change vs R8: carry + h0 preloaded into registers ONCE (8 float4 each);
// the three W_ih row-dots are branch-free fully-unrolled 8-load bursts
// (8 KB in flight per wave) so the load pipeline never breaks; the W_hh
// pass is separate, gated per 1KB chunk by the precomputed nz mask
// (bit-identical skip: fmaf(w,0,acc)==acc for finite w).
__global__ __launch_bounds__(256) void gru_layer_kernel(
    const float* __restrict__ Wi,    // [3H, H] this layer
    const float* __restrict__ Wh,    // [3H, H] this layer
    const float* __restrict__ bi,    // [3H]
    const float* __restrict__ bh,    // [3H]
    const float* __restrict__ hprev, // [H] = h0[l]
    const float* __restrict__ cin,   // [H]
    float* __restrict__ cout,        // [H]
    float* __restrict__ hid_out) {   // [H] slice of d_out
    const int e    = (blockIdx.x * blockDim.x + threadIdx.x) >> 6;  // element
    const int lane = threadIdx.x & 63;
    if (e >= H) return;

    // Preload vectors (8 KB each, L2-hot after first waves).
    float4 cv[8], hv[8];
    #pragma unroll
    for (int p = 0; p < 8; ++p) {
        int idx = p * 256 + lane * 4;
        cv[p] = *reinterpret_cast<const float4*>(cin + idx);
        hv[p] = *reinterpret_cast<const float4*>(hprev + idx);
    }
    int nz[8];
    #pragma unroll
    for (int p = 0; p < 8; ++p)
        nz[p] = __any((hv[p].x != 0.f) || (hv[p].y != 0.f) ||
                      (hv[p].z != 0.f) || (hv[p].w != 0.f));

    // W_ih dots: 3 rows, each a branch-free burst of 8 float4 loads.
    float ai[3];
    #pragma unroll
    for (int r = 0; r < 3; ++r) {
        const float* row = Wi + (size_t)(e + r * H) * H;
        float4 wv[8];
        #pragma unroll
        for (int p = 0; p < 8; ++p)
            wv[p] = *reinterpret_cast<const float4*>(row + p * 256 + lane * 4);
        float acc = 0.f;
        #pragma unroll
        for (int p = 0; p < 8; ++p) acc = dot4(wv[p], cv[p], acc);
        ai[r] = acc;
    }
    // W_hh dots: chunk-gated by nz (zero traffic when h0 == 0).
    float ah[3];
    #pragma unroll
    for (int r = 0; r < 3; ++r) {
        const float* row = Wh + (size_t)(e + r * H) * H;
        float acc = 0.f;
        #pragma unroll
        for (int p = 0; p < 8; ++p)
            if (nz[p])
                acc = dot4(*reinterpret_cast<const float4*>(row + p * 256 + lane * 4),
                           hv[p], acc);
        ah[r] = acc;
    }

    float s0 = wave_reduce_sum(ai[0]);
    float s1 = wave_reduce_sum(ai[1]);
    float s2 = wave_reduce_sum(ai[2]);
    float t0 = wave_reduce_sum(ah[0]);
    float t1 = wave_reduce_sum(ah[1]);
    float t2 = wave_reduce_sum(ah[2]);
    if (lane == 0) {
        float r = 1.f / (1.f + expf(-(s0 + bi[e] + t0 + bh[e])));
        float z = 1.f / (1.f + expf(-(s1 + bi[H + e] + t1 + bh[H + e])));
        float n = tanhf(s2 + bi[2 * H + e] + r * (t2 + bh[2 * H + e]));
        float h = hprev[e];
        float hnew = (1.f - z) * n + z * h;
        cout[e] = hnew;
        hid_out[e] = hnew;
    }
}

extern "C" void kernel_launch(void* const* d_in, const int* in_sizes, int n_in,
                              void* d_out, int out_size, void* d_ws, size_t ws_size,
                              hipStream_t stream) {
    const float* x    = (const float*)d_in[0];
    const float* h0   = (const float*)d_in[1];
    const float* encW = (const float*)d_in[2];
    const float* encb = (const float*)d_in[3];
    const float* Wih  = (const float*)d_in[4];
    const float* Whh  = (const float*)d_in[5];
    const float* bih  = (const float*)d_in[6];
    const float* bhh  = (const float*)d_in[7];
    const float* decW = (const float*)d_in[8];
    const float* decb = (const float*)d_in[9];
    float* out = (float*)d_out;

    float* vec0 = (float*)d_ws;      // [H]
    float* vec1 = vec0 + H;          // [H]

    // 1) encoder: [1,1024] -> [1,2048]
    gemv_kernel<DIN><<<H / 4, 256, 0, stream>>>(encW, x, encb, vec0, H);
    // 2) sequential fused GRU layers, ping-pong carry
    const float* cin = vec0;
    float* cout = vec1;
    for (int l = 0; l < NL; ++l) {
        gru_layer_kernel<<<H / 4, 256, 0, stream>>>(
            Wih + (size_t)l * 3 * H * H, Whh + (size_t)l * 3 * H * H,
            bih + l * 3 * H, bhh + l * 3 * H,
            h0 + l * H, cin, cout, out + DOUT + l * H);
        float* t = cout; cout = (float*)cin; cin = t;
    }
    // 3) decoder: [1,2048] -> [1,1024]
    gemv_kernel<H><<<DOUT / 4, 256, 0, stream>>>(decW, cin, decb, out, DOUT);
}